// Round 9
// baseline (131.734 us; speedup 1.0000x reference)
//
#include <hip/hip_runtime.h>

// LabelizerNet: avg-pool(6,2) -> RGB->HSV -> yellow/blue mask -> per-panel max/min
// Input : states (N, 3, 84, 84) f32   (N = 4096)
// Output: labels (N, 6) f32  [yellow panels 0..2, blue panels 0..2]
//
// Round 9: round-7 structure + NON-TEMPORAL loads (nt bit) on the once-through
// input stream, bypassing L2/LLC allocation churn (347 MB through a 256 MB
// LLC). Math is verbatim round 7 -> bit-identical results.

#define IMG_H 84
#define IMG_W 84
#define CH_ELEMS (IMG_H * IMG_W)   // 7056
#define PAIRS_W 20                 // pixel-pair columns
#define ROW_PAIRS 7                // input row-pairs per chunk (rows 0..13)
#define ITEMS_PER_IMG 160          // PAIRS_W * 8 chunks

typedef float f4 __attribute__((ext_vector_type(4)));

__global__ __launch_bounds__(64, 4)
void pool_mask_kernel(const float* __restrict__ in, unsigned* __restrict__ ws,
                      int total_items) {
    const int lane = threadIdx.x;
    const int gi = blockIdx.x * 64 + lane;

    const int img  = gi / ITEMS_PER_IMG;
    const int item = gi - img * ITEMS_PER_IMG;

    unsigned my = 0u;

    if (gi < total_items) {
        const int chunk = item / PAIRS_W;          // 0..7
        const int xp = item - chunk * PAIRS_W;     // 0..19
        const int x0 = 2 * xp, x1 = 2 * xp + 1;
        const int R0 = chunk * 10;                 // first input row
        const float* cb0 = in + (size_t)img * (3 * CH_ELEMS) + R0 * IMG_W + 4 * xp;

        float prevP0[3], prevS0[3], prevP1[3], prevS1[3];

        #pragma unroll
        for (int j = 0; j < ROW_PAIRS; ++j) {
            float t0[3], t1[3];
            #pragma unroll
            for (int c = 0; c < 3; ++c) {
                const float* rbase = cb0 + c * CH_ELEMS + (2 * j) * IMG_W;
                const f4* ra = (const f4*)rbase;            // row 2j
                const f4* rb = (const f4*)(rbase + IMG_W);  // row 2j+1
                f4 qa0 = __builtin_nontemporal_load(ra);
                f4 qa1 = __builtin_nontemporal_load(ra + 1);
                f4 qb0 = __builtin_nontemporal_load(rb);
                f4 qb1 = __builtin_nontemporal_load(rb + 1);
                float a01 = qa0.x + qa0.y, a23 = qa0.z + qa0.w;
                float a45 = qa1.x + qa1.y, a67 = qa1.z + qa1.w;
                float rsa0 = (a01 + a23) + a45;      // rs[2j],  window x0
                float rsa1 = (a23 + a45) + a67;      // rs[2j],  window x1
                float b01 = qb0.x + qb0.y, b23 = qb0.z + qb0.w;
                float b45 = qb1.x + qb1.y, b67 = qb1.z + qb1.w;
                float rsb0 = (b01 + b23) + b45;      // rs[2j+1], window x0
                float rsb1 = (b23 + b45) + b67;      // rs[2j+1], window x1
                float P0 = rsa0 + rsb0;              // pair sum == rs[2j]+rs[2j+1]
                float P1 = rsa1 + rsb1;
                if (j >= 2) {                        // finalize output row o=j-2
                    t0[c] = prevS0[c] + P0;          // (P_o+P_{o+1}) + P_{o+2}
                    t1[c] = prevS1[c] + P1;
                }
                if (j >= 1) {
                    prevS0[c] = prevP0[c] + P0;      // P_{j-1} + P_j
                    prevS1[c] = prevP1[c] + P1;
                }
                prevP0[c] = P0;
                prevP1[c] = P1;
            }
            if (j >= 2) {
                #pragma unroll
                for (int e = 0; e < 2; ++e) {
                    float r = ((e == 0) ? t0[0] : t1[0]) / 36.0f;
                    float g = ((e == 0) ? t0[1] : t1[1]) / 36.0f;
                    float b = ((e == 0) ? t0[2] : t1[2]) / 36.0f;

                    float maxc = fmaxf(r, fmaxf(g, b));
                    float minc = fminf(r, fminf(g, b));
                    float delta = maxc - minc;
                    float s = (maxc == 0.0f) ? 0.0f : delta / maxc;
                    float v = maxc;
                    float h = 0.0f;
                    if (delta != 0.0f) {
                        float rc = (maxc - r) / delta;
                        float gc = (maxc - g) / delta;
                        float bc = (maxc - b) / delta;
                        float hh = (r == maxc) ? (bc - gc)
                                 : ((g == maxc) ? (2.0f + rc - bc)
                                                : (4.0f + gc - rc));
                        h = hh / 6.0f;           // in (-1/6, 5/6); floor-mod 1:
                        if (h < 0.0f) h += 1.0f;
                    }
                    bool satval = (s > 0.5f) && (v > 0.5f);
                    int m = 0;
                    if (satval && h >= 0.1f && h <= 0.2f) m = 1;
                    else if (satval && h >= 0.55f && h <= 0.7f) m = -1;

                    int x = (e == 0) ? x0 : x1;
                    if (x < 39) {                 // col 39 excluded (40//3*3 == 39)
                        int pan = x / 13;         // 0..2
                        unsigned bit = (m > 0) ? 1u : (m < 0) ? 2u : 4u;
                        my |= bit << (3 * pan);
                    }
                }
            }
        }
    }

    // A wave spans at most 2 images (64 < 160). Reduce each separately.
    const int imgA = __shfl(img, 0);
    const int imgB = __shfl(img, 63);
    unsigned vA = (img == imgA) ? my : 0u;
    #pragma unroll
    for (int off = 32; off > 0; off >>= 1) vA |= __shfl_xor(vA, off);
    if (lane == 0 && vA) atomicOr(&ws[imgA], vA);
    if (imgB != imgA) {
        unsigned vB = (img == imgB) ? my : 0u;
        #pragma unroll
        for (int off = 32; off > 0; off >>= 1) vB |= __shfl_xor(vB, off);
        if (lane == 0 && vB) atomicOr(&ws[imgB], vB);
    }
}

__global__ __launch_bounds__(256)
void finalize_kernel(const unsigned* __restrict__ ws, float* __restrict__ out, int N) {
    int i = blockIdx.x * 256 + threadIdx.x;
    if (i < N * 6) {
        int img = i / 6;
        int j = i - img * 6;
        int pan = (j < 3) ? j : j - 3;
        unsigned w = ws[img] >> (3 * pan);
        bool anyY = w & 1u;
        bool anyB = (w >> 1) & 1u;
        bool anyZ = (w >> 2) & 1u;
        float val;
        if (j < 3) val = anyY ? 1.0f : (anyZ ? 0.0f : -1.0f);   // max(panel)
        else       val = anyB ? 1.0f : (anyZ ? 0.0f : -1.0f);   // -min(panel)
        out[i] = val;
    }
}

extern "C" void kernel_launch(void* const* d_in, const int* in_sizes, int n_in,
                              void* d_out, int out_size, void* d_ws, size_t ws_size,
                              hipStream_t stream) {
    const float* states = (const float*)d_in[0];
    float* out = (float*)d_out;
    unsigned* ws = (unsigned*)d_ws;
    int N = in_sizes[0] / (3 * CH_ELEMS);   // 4096
    int total_items = N * ITEMS_PER_IMG;    // 655360

    hipMemsetAsync(ws, 0, (size_t)N * sizeof(unsigned), stream);
    int blocks1 = (total_items + 63) / 64;  // 10240
    pool_mask_kernel<<<blocks1, 64, 0, stream>>>(states, ws, total_items);
    int blocks2 = (N * 6 + 255) / 256;
    finalize_kernel<<<blocks2, 256, 0, stream>>>(ws, out, N);
}

// Round 10
// 87.742 us; speedup vs baseline: 1.5014x; 1.5014x over previous
//
#include <hip/hip_runtime.h>

// LabelizerNet: avg-pool(6,2) -> RGB->HSV -> yellow/blue mask -> per-panel max/min
// Input : states (N, 3, 84, 84) f32   (N = 4096)
// Output: labels (N, 6) f32  [yellow panels 0..2, blue panels 0..2]
//
// Round 10: round-8 skeleton with global_load_lds (direct-to-LDS DMA) staging.
// Tests whether the DMA path sustains more outstanding cacheline misses per CU
// than VGPR-return loads (the ~3.3 TB/s wall seen in rounds 3/6/7/8).
// Compute math verbatim round 8 -> bit-identical results.

#define CH_ELEMS 7056              // 84*84
#define IMG_F4   5292              // 3*7056/4
#define CH_F4    1764              // 7056/4
#define ROW_F4   21                // 84/4
#define STG_F4   924               // 44 rows * 21 float4 per channel
#define LDS_CH   3696              // 44*84 floats
#define ROW_STR  84

__device__ __forceinline__ void gl_lds16(const float4* g, float4* l) {
    __builtin_amdgcn_global_load_lds(
        (const __attribute__((address_space(1))) void*)(uintptr_t)(const void*)g,
        (__attribute__((address_space(3))) void*)(uintptr_t)(void*)l,
        16, 0, 0);
}

__global__ __launch_bounds__(256, 3)
void pool_mask_kernel(const float* __restrict__ in, unsigned* __restrict__ ws) {
    __shared__ float4 s4[3 * STG_F4];      // 44352 B

    const int tid  = threadIdx.x;
    const int img  = blockIdx.x >> 1;
    const int half = blockIdx.x & 1;
    const int R0   = half * 40;            // input row base (rows R0..R0+43)

    // ---- stage 3 sequential segments of 14784 B each via direct-to-LDS DMA ----
    // LDS dest is wave-uniform base + lane*16 (m104): each wave-chunk k writes
    // the lane-linear span [k*64, k*64+63] of the channel's float4 region.
    const float4* src = (const float4*)in + (size_t)img * IMG_F4 + R0 * ROW_F4;
    const int wid = tid >> 6, lane = tid & 63;
    #pragma unroll
    for (int c = 0; c < 3; ++c) {
        const float4* sc = src + c * CH_F4;
        float4* dc = s4 + c * STG_F4;
        for (int k = wid; k < 14; k += 4) {      // 14*64 = 896 float4
            int i = k * 64 + lane;
            gl_lds16(sc + i, dc + i);
        }
        if (tid < STG_F4 - 896)                  // 28-float4 tail, plain path
            dc[896 + tid] = sc[896 + tid];
    }
    __syncthreads();   // drains vmcnt (DMA) + lgkmcnt (tail ds_write)

    // ---- compute: item = (2-pooled-row chunk, pair-column) ----
    unsigned my = 0u;
    if (tid < 200) {
        const int chunk = tid / 20;          // 0..9  -> pooled rows 2c,2c+1
        const int xp    = tid - chunk * 20;  // 0..19
        const int x0 = 2 * xp, x1 = 2 * xp + 1;
        const float* sf = (const float*)s4;
        const int lbase = 4 * chunk * ROW_STR + 4 * xp;   // local row 4c, col 4xp

        float prevP0[3], prevS0[3], prevP1[3], prevS1[3];

        #pragma unroll
        for (int j = 0; j < 4; ++j) {        // row-pairs P_0..P_3
            float t0[3], t1[3];
            #pragma unroll
            for (int c = 0; c < 3; ++c) {
                const float* rbase = sf + c * LDS_CH + lbase + (2 * j) * ROW_STR;
                const float4* ra = (const float4*)rbase;            // row 2j
                const float4* rb = (const float4*)(rbase + ROW_STR);// row 2j+1
                float4 qa0 = ra[0], qa1 = ra[1];
                float4 qb0 = rb[0], qb1 = rb[1];
                float a01 = qa0.x + qa0.y, a23 = qa0.z + qa0.w;
                float a45 = qa1.x + qa1.y, a67 = qa1.z + qa1.w;
                float rsa0 = (a01 + a23) + a45;      // rs[2j],  window x0
                float rsa1 = (a23 + a45) + a67;      // rs[2j],  window x1
                float b01 = qb0.x + qb0.y, b23 = qb0.z + qb0.w;
                float b45 = qb1.x + qb1.y, b67 = qb1.z + qb1.w;
                float rsb0 = (b01 + b23) + b45;      // rs[2j+1], window x0
                float rsb1 = (b23 + b45) + b67;      // rs[2j+1], window x1
                float P0 = rsa0 + rsb0;
                float P1 = rsa1 + rsb1;
                if (j >= 2) {                        // finalize pooled row 2c+(j-2)
                    t0[c] = prevS0[c] + P0;          // (P_o+P_{o+1}) + P_{o+2}
                    t1[c] = prevS1[c] + P1;
                }
                if (j >= 1) {
                    prevS0[c] = prevP0[c] + P0;
                    prevS1[c] = prevP1[c] + P1;
                }
                prevP0[c] = P0;
                prevP1[c] = P1;
            }
            if (j >= 2) {
                #pragma unroll
                for (int e = 0; e < 2; ++e) {
                    float r = ((e == 0) ? t0[0] : t1[0]) / 36.0f;
                    float g = ((e == 0) ? t0[1] : t1[1]) / 36.0f;
                    float b = ((e == 0) ? t0[2] : t1[2]) / 36.0f;

                    float maxc = fmaxf(r, fmaxf(g, b));
                    float minc = fminf(r, fminf(g, b));
                    float delta = maxc - minc;
                    float s = (maxc == 0.0f) ? 0.0f : delta / maxc;
                    float v = maxc;
                    float h = 0.0f;
                    if (delta != 0.0f) {
                        float rc = (maxc - r) / delta;
                        float gc = (maxc - g) / delta;
                        float bc = (maxc - b) / delta;
                        float hh = (r == maxc) ? (bc - gc)
                                 : ((g == maxc) ? (2.0f + rc - bc)
                                                : (4.0f + gc - rc));
                        h = hh / 6.0f;           // in (-1/6, 5/6); floor-mod 1:
                        if (h < 0.0f) h += 1.0f;
                    }
                    bool satval = (s > 0.5f) && (v > 0.5f);
                    int m = 0;
                    if (satval && h >= 0.1f && h <= 0.2f) m = 1;
                    else if (satval && h >= 0.55f && h <= 0.7f) m = -1;

                    int x = (e == 0) ? x0 : x1;
                    if (x < 39) {                 // col 39 excluded (40//3*3 == 39)
                        int pan = x / 13;         // 0..2
                        unsigned bit = (m > 0) ? 1u : (m < 0) ? 2u : 4u;
                        my |= bit << (3 * pan);
                    }
                }
            }
        }
    }

    // whole block is one image: wave OR-reduce, one device atomic per wave
    #pragma unroll
    for (int off = 32; off > 0; off >>= 1) my |= __shfl_xor(my, off);
    if ((tid & 63) == 0 && my) atomicOr(&ws[img], my);
}

__global__ __launch_bounds__(256)
void finalize_kernel(const unsigned* __restrict__ ws, float* __restrict__ out, int N) {
    int i = blockIdx.x * 256 + threadIdx.x;
    if (i < N * 6) {
        int img = i / 6;
        int j = i - img * 6;
        int pan = (j < 3) ? j : j - 3;
        unsigned w = ws[img] >> (3 * pan);
        bool anyY = w & 1u;
        bool anyB = (w >> 1) & 1u;
        bool anyZ = (w >> 2) & 1u;
        float val;
        if (j < 3) val = anyY ? 1.0f : (anyZ ? 0.0f : -1.0f);   // max(panel)
        else       val = anyB ? 1.0f : (anyZ ? 0.0f : -1.0f);   // -min(panel)
        out[i] = val;
    }
}

extern "C" void kernel_launch(void* const* d_in, const int* in_sizes, int n_in,
                              void* d_out, int out_size, void* d_ws, size_t ws_size,
                              hipStream_t stream) {
    const float* states = (const float*)d_in[0];
    float* out = (float*)d_out;
    unsigned* ws = (unsigned*)d_ws;
    int N = in_sizes[0] / (3 * CH_ELEMS);   // 4096

    hipMemsetAsync(ws, 0, (size_t)N * sizeof(unsigned), stream);
    pool_mask_kernel<<<2 * N, 256, 0, stream>>>(states, ws);
    int blocks2 = (N * 6 + 255) / 256;
    finalize_kernel<<<blocks2, 256, 0, stream>>>(ws, out, N);
}